// Round 6
// baseline (9080.510 us; speedup 1.0000x reference)
//
#include <hip/hip_runtime.h>

// WaveNet_33036888440853: out[b] = sum_c det( mo[b][cfg[c],cfg[c]] ) * W_ci[c]
// mo = x @ W_mo^T.  B=1024, NE=NAO=NMO=128, NC=32, D=64.  All fp32.
// One block (256 thr) per batch b. mo[b] in LDS; 32 LU dets (64x64),
// rows-in-lanes, columns in scalar regs (a[64], fully-unrolled k-loop ->
// static indices -> stays in VGPRs; round-4/5 b128-quad variant was demoted
// to scratch when the bigger body failed to unroll: 6x regression).
// This round: 2 LUs interleaved per wave (2x ILP) to hide the per-k serial
// pivot chain (ballot -> readlane -> rcp/NR), which left VALU ~44% busy.
// Pivoting: diagonal-first threshold (tau=0.02), shuffle-max backstop.

constexpr int NE  = 128;
constexpr int NAO = 128;
constexpr int D   = 64;

constexpr int MOS = 129;  // mo_ls stride: (129R+c)%32=(R+c)%32 -> ~2-way on gather
constexpr int GS  = 132;  // staging stride: mult of 4 (aligned b128)

constexpr float TAU = 0.02f;  // mo entries ~ N(0, 0.2^2); P(|diag|<tau) ~ 8%

__device__ __forceinline__ float readlane_f(float v, int lane) {
  return __int_as_float(__builtin_amdgcn_readlane(__float_as_int(v), lane));
}

__global__ __launch_bounds__(256, 2) void wavenet_kernel(
    const float* __restrict__ x, const float* __restrict__ W_mo,
    const float* __restrict__ W_ci, const int* __restrict__ configs,
    float* __restrict__ out) {
  __shared__ alignas(16) float mo_ls[128 * MOS];
  __shared__ alignas(16) float x_ls[8 * GS];
  __shared__ alignas(16) float w_ls[8 * GS];
  __shared__ float partial[4];

  const int t    = threadIdx.x;
  const int b    = blockIdx.x;
  const int lane = t & 63;
  const int w    = t >> 6;

  // ---------------- Phase 1: mo_ls = x[b] @ W_mo^T (128x128) ----------------
  const int tx = t & 15, ty = t >> 4;
  const int c0 = tx * 8, r0 = ty * 8;
  const float* xb = x + (size_t)b * NE * NAO;

  float acc[8][8];
#pragma unroll
  for (int i = 0; i < 8; ++i)
#pragma unroll
    for (int j = 0; j < 8; ++j) acc[i][j] = 0.f;

  const int le = t >> 1;        // staging row 0..127
  const int lh = (t & 1) * 4;   // k-half 0 or 4

  for (int kb = 0; kb < 16; ++kb) {  // BK = 8
    const float4 xv = *reinterpret_cast<const float4*>(xb + le * NAO + kb * 8 + lh);
    const float4 wv = *reinterpret_cast<const float4*>(W_mo + le * NAO + kb * 8 + lh);
    x_ls[(lh + 0) * GS + le] = xv.x;
    x_ls[(lh + 1) * GS + le] = xv.y;
    x_ls[(lh + 2) * GS + le] = xv.z;
    x_ls[(lh + 3) * GS + le] = xv.w;
    w_ls[(lh + 0) * GS + le] = wv.x;
    w_ls[(lh + 1) * GS + le] = wv.y;
    w_ls[(lh + 2) * GS + le] = wv.z;
    w_ls[(lh + 3) * GS + le] = wv.w;
    __syncthreads();
#pragma unroll
    for (int nn = 0; nn < 8; ++nn) {
      const float4 a0 = *reinterpret_cast<const float4*>(&x_ls[nn * GS + r0]);
      const float4 a1 = *reinterpret_cast<const float4*>(&x_ls[nn * GS + r0 + 4]);
      const float4 b0 = *reinterpret_cast<const float4*>(&w_ls[nn * GS + c0]);
      const float4 b1 = *reinterpret_cast<const float4*>(&w_ls[nn * GS + c0 + 4]);
      const float av[8] = {a0.x, a0.y, a0.z, a0.w, a1.x, a1.y, a1.z, a1.w};
      const float bv[8] = {b0.x, b0.y, b0.z, b0.w, b1.x, b1.y, b1.z, b1.w};
#pragma unroll
      for (int i = 0; i < 8; ++i)
#pragma unroll
        for (int j = 0; j < 8; ++j) acc[i][j] = fmaf(av[i], bv[j], acc[i][j]);
    }
    __syncthreads();
  }
#pragma unroll
  for (int i = 0; i < 8; ++i)
#pragma unroll
    for (int j = 0; j < 8; ++j) mo_ls[(r0 + i) * MOS + c0 + j] = acc[i][j];
  __syncthreads();

  // -------- Phase 2: 8 LUs per wave, processed 2-at-a-time (ILP) -----------
  float waveacc = 0.f;

#pragma unroll 1
  for (int cc = 0; cc < 4; ++cc) {
    const int cA = w * 8 + cc * 2;
    const int cB = cA + 1;
    const int cjvA = configs[cA * D + lane];
    const int cjvB = configs[cB * D + lane];
    const int baseA = cjvA * MOS;
    const int baseB = cjvB * MOS;

    float aA[64], aB[64];
#pragma unroll
    for (int j = 0; j < 64; ++j) {
      aA[j] = mo_ls[baseA + __builtin_amdgcn_readlane(cjvA, j)];
      aB[j] = mo_ls[baseB + __builtin_amdgcn_readlane(cjvB, j)];
    }

    int slotA = lane, slotB = lane;
    float detA = 1.f, detB = 1.f;

#pragma unroll
    for (int k = 0; k < 64; ++k) {
      // ---------------- LU A: pivot step k ----------------
      {
        const float ak = aA[k];
        unsigned long long dbal = __ballot(slotA == k);
        int   p  = (int)__builtin_ctzll(dbal);
        float pv = readlane_f(ak, p);
        if (!(fabsf(pv) > TAU)) {  // wave-uniform, rare
          const bool act = (slotA >= k);
          unsigned long long cbal = __ballot(act && (fabsf(ak) > TAU));
          if (cbal == 0ull) {
            float v = act ? fabsf(ak) : -1.f;
#pragma unroll
            for (int off = 32; off; off >>= 1) v = fmaxf(v, __shfl_xor(v, off));
            cbal = __ballot(act && (fabsf(ak) == v));
            if (cbal == 0ull) cbal = __ballot(act);
          }
          p  = (int)__builtin_ctzll(cbal);
          pv = readlane_f(ak, p);
          const int sp = __builtin_amdgcn_readlane(slotA, p);
          if (sp != k) detA = -detA;
          slotA = (lane == p) ? k : ((slotA == k) ? sp : slotA);
        }
        float invp;
        if (pv != 0.f) {
          invp = __builtin_amdgcn_rcpf(pv);
          invp = invp * (2.f - pv * invp);
          detA *= pv;
        } else {
          detA = 0.f;
          invp = 0.f;
        }
        const float m = (slotA > k) ? ak * invp : 0.f;
#pragma unroll
        for (int j = k + 1; j < 64; ++j)
          aA[j] = fmaf(-m, readlane_f(aA[j], p), aA[j]);
      }
      // ---------------- LU B: pivot step k ----------------
      {
        const float ak = aB[k];
        unsigned long long dbal = __ballot(slotB == k);
        int   p  = (int)__builtin_ctzll(dbal);
        float pv = readlane_f(ak, p);
        if (!(fabsf(pv) > TAU)) {  // wave-uniform, rare
          const bool act = (slotB >= k);
          unsigned long long cbal = __ballot(act && (fabsf(ak) > TAU));
          if (cbal == 0ull) {
            float v = act ? fabsf(ak) : -1.f;
#pragma unroll
            for (int off = 32; off; off >>= 1) v = fmaxf(v, __shfl_xor(v, off));
            cbal = __ballot(act && (fabsf(ak) == v));
            if (cbal == 0ull) cbal = __ballot(act);
          }
          p  = (int)__builtin_ctzll(cbal);
          pv = readlane_f(ak, p);
          const int sp = __builtin_amdgcn_readlane(slotB, p);
          if (sp != k) detB = -detB;
          slotB = (lane == p) ? k : ((slotB == k) ? sp : slotB);
        }
        float invp;
        if (pv != 0.f) {
          invp = __builtin_amdgcn_rcpf(pv);
          invp = invp * (2.f - pv * invp);
          detB *= pv;
        } else {
          detB = 0.f;
          invp = 0.f;
        }
        const float m = (slotB > k) ? ak * invp : 0.f;
#pragma unroll
        for (int j = k + 1; j < 64; ++j)
          aB[j] = fmaf(-m, readlane_f(aB[j], p), aB[j]);
      }
    }
    waveacc += detA * W_ci[cA] + detB * W_ci[cB];
  }

  if (lane == 0) partial[w] = waveacc;
  __syncthreads();
  if (t == 0) out[b] = partial[0] + partial[1] + partial[2] + partial[3];
}

extern "C" void kernel_launch(void* const* d_in, const int* in_sizes, int n_in,
                              void* d_out, int out_size, void* d_ws, size_t ws_size,
                              hipStream_t stream) {
  (void)in_sizes; (void)n_in; (void)d_ws; (void)ws_size; (void)out_size;
  const float* x       = (const float*)d_in[0];
  const float* W_mo    = (const float*)d_in[1];
  const float* W_ci    = (const float*)d_in[2];
  const int*   configs = (const int*)d_in[3];
  float*       out     = (float*)d_out;
  hipLaunchKernelGGL(wavenet_kernel, dim3(1024), dim3(256), 0, stream,
                     x, W_mo, W_ci, configs, out);
}

// Round 7
// 1841.244 us; speedup vs baseline: 4.9317x; 4.9317x over previous
//
#include <hip/hip_runtime.h>

// WaveNet_33036888440853: out[b] = sum_c det( mo[b][cfg[c],cfg[c]] ) * W_ci[c]
// mo = x @ W_mo^T.  B=1024, NE=NAO=NMO=128, NC=32, D=64.  All fp32.
// One block (256 thr) per batch b. mo[b] in LDS; 32 LU dets (64x64),
// rows-in-lanes, columns in scalar regs a[64] (fully-unrolled triangular
// loops -> static indices -> registers; bigger bodies (r4/r5 quad-chunks,
// r6 dual-LU) broke the unroller -> scratch -> 6-18x regressions).
// This round: pivot-row broadcast via scalar LDS write/read (ds_write_b32 by
// pivot lane, same-address ds_read_b32 broadcast by all lanes) instead of
// per-element v_readlane -> halves VALU inst in the elimination inner loop;
// DS pipe overlaps the co-resident wave's VALU.
// Pivoting: diagonal-first threshold (tau=0.02), shuffle-max backstop.

constexpr int NE  = 128;
constexpr int NAO = 128;
constexpr int D   = 64;

constexpr int MOS = 129;  // mo_ls stride: (129R+c)%32=(R+c)%32 -> ~2-way on gather
constexpr int GS  = 132;  // staging stride: mult of 4 (aligned b128)

constexpr float TAU = 0.02f;  // mo entries ~ N(0, 0.2^2); P(|diag|<tau) ~ 8%

__device__ __forceinline__ float readlane_f(float v, int lane) {
  return __int_as_float(__builtin_amdgcn_readlane(__float_as_int(v), lane));
}

__global__ __launch_bounds__(256, 2) void wavenet_kernel(
    const float* __restrict__ x, const float* __restrict__ W_mo,
    const float* __restrict__ W_ci, const int* __restrict__ configs,
    float* __restrict__ out) {
  __shared__ alignas(16) float mo_ls[128 * MOS];
  __shared__ alignas(16) float x_ls[8 * GS];
  __shared__ alignas(16) float w_ls[8 * GS];
  __shared__ float partial[4];

  const int t    = threadIdx.x;
  const int b    = blockIdx.x;
  const int lane = t & 63;
  const int w    = t >> 6;

  // ---------------- Phase 1: mo_ls = x[b] @ W_mo^T (128x128) ----------------
  const int tx = t & 15, ty = t >> 4;
  const int c0 = tx * 8, r0 = ty * 8;
  const float* xb = x + (size_t)b * NE * NAO;

  float acc[8][8];
#pragma unroll
  for (int i = 0; i < 8; ++i)
#pragma unroll
    for (int j = 0; j < 8; ++j) acc[i][j] = 0.f;

  const int le = t >> 1;        // staging row 0..127
  const int lh = (t & 1) * 4;   // k-half 0 or 4

  for (int kb = 0; kb < 16; ++kb) {  // BK = 8
    const float4 xv = *reinterpret_cast<const float4*>(xb + le * NAO + kb * 8 + lh);
    const float4 wv = *reinterpret_cast<const float4*>(W_mo + le * NAO + kb * 8 + lh);
    x_ls[(lh + 0) * GS + le] = xv.x;
    x_ls[(lh + 1) * GS + le] = xv.y;
    x_ls[(lh + 2) * GS + le] = xv.z;
    x_ls[(lh + 3) * GS + le] = xv.w;
    w_ls[(lh + 0) * GS + le] = wv.x;
    w_ls[(lh + 1) * GS + le] = wv.y;
    w_ls[(lh + 2) * GS + le] = wv.z;
    w_ls[(lh + 3) * GS + le] = wv.w;
    __syncthreads();
#pragma unroll
    for (int nn = 0; nn < 8; ++nn) {
      const float4 a0 = *reinterpret_cast<const float4*>(&x_ls[nn * GS + r0]);
      const float4 a1 = *reinterpret_cast<const float4*>(&x_ls[nn * GS + r0 + 4]);
      const float4 b0 = *reinterpret_cast<const float4*>(&w_ls[nn * GS + c0]);
      const float4 b1 = *reinterpret_cast<const float4*>(&w_ls[nn * GS + c0 + 4]);
      const float av[8] = {a0.x, a0.y, a0.z, a0.w, a1.x, a1.y, a1.z, a1.w};
      const float bv[8] = {b0.x, b0.y, b0.z, b0.w, b1.x, b1.y, b1.z, b1.w};
#pragma unroll
      for (int i = 0; i < 8; ++i)
#pragma unroll
        for (int j = 0; j < 8; ++j) acc[i][j] = fmaf(av[i], bv[j], acc[i][j]);
    }
    __syncthreads();
  }
#pragma unroll
  for (int i = 0; i < 8; ++i)
#pragma unroll
    for (int j = 0; j < 8; ++j) mo_ls[(r0 + i) * MOS + c0 + j] = acc[i][j];
  __syncthreads();  // x_ls/w_ls dead after this -> per-wave rowbuf overlays x_ls

  // ---------------- Phase 2: 8 LUs per wave, no block barriers --------------
  float waveacc = 0.f;
  volatile float* rb = (volatile float*)&x_ls[w * 64];  // per-wave rowbuf

#pragma unroll 1
  for (int cc = 0; cc < 8; ++cc) {
    const int c = w * 8 + cc;
    const int cjv     = configs[c * D + lane];  // lane's row config index
    const int rowbase = cjv * MOS;

    float a[64];
#pragma unroll
    for (int j = 0; j < 64; ++j) {
      const int cj = __builtin_amdgcn_readlane(cjv, j);  // column config index
      a[j] = mo_ls[rowbase + cj];
    }

    int myslot = lane;   // virtual row-slot (tracks permutation for sign)
    float det  = 1.f;

#pragma unroll
    for (int k = 0; k < 64; ++k) {
      const float ak = a[k];
      // --- pivot selection: diagonal-first threshold pivoting ---
      unsigned long long dbal = __ballot(myslot == k);
      int   p  = (int)__builtin_ctzll(dbal);
      float pv = readlane_f(ak, p);

      if (!(fabsf(pv) > TAU)) {  // wave-uniform, rare (~8%)
        const bool act = (myslot >= k);
        unsigned long long cbal = __ballot(act && (fabsf(ak) > TAU));
        if (cbal == 0ull) {      // very rare: all candidates tiny -> true max
          float v = act ? fabsf(ak) : -1.f;
#pragma unroll
          for (int off = 32; off; off >>= 1) v = fmaxf(v, __shfl_xor(v, off));
          cbal = __ballot(act && (fabsf(ak) == v));
          if (cbal == 0ull) cbal = __ballot(act);  // paranoia
        }
        p  = (int)__builtin_ctzll(cbal);
        pv = readlane_f(ak, p);
        // swap + sign (LAPACK p!=k rule in slot space)
        const int sp = __builtin_amdgcn_readlane(myslot, p);
        if (sp != k) det = -det;
        myslot = (lane == p) ? k : ((myslot == k) ? sp : myslot);
      }

      float invp;
      if (pv != 0.f) {
        invp = __builtin_amdgcn_rcpf(pv);
        invp = invp * (2.f - pv * invp);  // one NR step
        det *= pv;
      } else {
        det  = 0.f;   // singular: freeze (invp=0 -> no-op updates)
        invp = 0.f;
      }

      // pivot lane publishes trailing row to LDS (scalar, static indices);
      // DS ops are in-order within a wave -> the broadcast reads below see
      // the writes; volatile pins the compiler's ordering.
      if (lane == p) {
#pragma unroll
        for (int j = k + 1; j < 64; ++j) rb[j] = a[j];
      }
      const float m = (myslot > k) ? ak * invp : 0.f;  // retired rows: no-op
#pragma unroll
      for (int j = k + 1; j < 64; ++j)
        a[j] = fmaf(-m, rb[j], a[j]);
    }
    waveacc += det * W_ci[c];
  }

  if (lane == 0) partial[w] = waveacc;
  __syncthreads();
  if (t == 0) out[b] = partial[0] + partial[1] + partial[2] + partial[3];
}

extern "C" void kernel_launch(void* const* d_in, const int* in_sizes, int n_in,
                              void* d_out, int out_size, void* d_ws, size_t ws_size,
                              hipStream_t stream) {
  (void)in_sizes; (void)n_in; (void)d_ws; (void)ws_size; (void)out_size;
  const float* x       = (const float*)d_in[0];
  const float* W_mo    = (const float*)d_in[1];
  const float* W_ci    = (const float*)d_in[2];
  const int*   configs = (const int*)d_in[3];
  float*       out     = (float*)d_out;
  hipLaunchKernelGGL(wavenet_kernel, dim3(1024), dim3(256), 0, stream,
                     x, W_mo, W_ci, configs, out);
}

// Round 8
// 542.539 us; speedup vs baseline: 16.7371x; 3.3938x over previous
//
#include <hip/hip_runtime.h>

// WaveNet_33036888440853: out[b] = sum_c det( mo[b][cfg[c],cfg[c]] ) * W_ci[c]
// mo = x @ W_mo^T.  B=1024, NE=NAO=NMO=128, NC=32, D=64.  All fp32.
// One 1024-thread block (16 waves) per batch b -> 4 waves/SIMD (vs 2 for the
// 256-thread variant, which was LDS-capped at 2 blocks/CU). Phase 2 is
// latency-bound on the per-k pivot chain (real VALU util ~22% in r3; the
// derived VALUBusy metric inflates ~4x on SIMD-32) -> more waves = hiding.
// Phase 2 per wave: 2 LUs, rows-in-lanes, columns in scalar regs a[64]
// (fully-unrolled triangular loops -> static indices -> registers; larger
// bodies broke the unroller -> scratch -> 6-18x regressions in r4/r5/r6).
// Broadcast via v_readlane (proven r3). Diagonal-first threshold pivoting
// (tau=0.02), shuffle-max backstop. rcp without NR (1-ulp rcp; 27x margin).

constexpr int NE  = 128;
constexpr int NAO = 128;
constexpr int D   = 64;

constexpr int MOS = 129;  // mo_ls stride: odd -> gather (R+c)%32 ~2-way max
constexpr int GS  = 132;  // staging stride: mult of 4 (aligned b128 reads)

constexpr float TAU = 0.02f;  // mo entries ~ N(0, 0.2^2); P(|diag|<tau) ~ 8%

__device__ __forceinline__ float readlane_f(float v, int lane) {
  return __int_as_float(__builtin_amdgcn_readlane(__float_as_int(v), lane));
}

__global__ __launch_bounds__(1024, 4) void wavenet_kernel(
    const float* __restrict__ x, const float* __restrict__ W_mo,
    const float* __restrict__ W_ci, const int* __restrict__ configs,
    float* __restrict__ out) {
  __shared__ alignas(16) float mo_ls[128 * MOS];   // 66.0 KB
  __shared__ alignas(16) float x_ls[32 * GS];      // 16.9 KB
  __shared__ alignas(16) float w_ls[32 * GS];      // 16.9 KB
  __shared__ float partial[16];

  const int t    = threadIdx.x;
  const int b    = blockIdx.x;
  const int lane = t & 63;
  const int w    = t >> 6;          // wave 0..15

  // ---------------- Phase 1: mo_ls = x[b] @ W_mo^T (128x128) ----------------
  // 1024 threads: 32x32 thread grid, 4x4 outputs each, BK=32.
  const int tx = t & 31, ty = t >> 5;
  const int c0 = tx * 4, r0 = ty * 4;
  const float* xb = x + (size_t)b * NE * NAO;

  float acc[4][4];
#pragma unroll
  for (int i = 0; i < 4; ++i)
#pragma unroll
    for (int j = 0; j < 4; ++j) acc[i][j] = 0.f;

  const int srow = t >> 3;          // staging row 0..127
  const int kq   = (t & 7) * 4;     // k-offset within 32-tile: 0,4,..,28

  for (int kb = 0; kb < 4; ++kb) {  // BK = 32
    const float4 xv = *reinterpret_cast<const float4*>(xb + srow * NAO + kb * 32 + kq);
    const float4 wv = *reinterpret_cast<const float4*>(W_mo + srow * NAO + kb * 32 + kq);
    x_ls[(kq + 0) * GS + srow] = xv.x;
    x_ls[(kq + 1) * GS + srow] = xv.y;
    x_ls[(kq + 2) * GS + srow] = xv.z;
    x_ls[(kq + 3) * GS + srow] = xv.w;
    w_ls[(kq + 0) * GS + srow] = wv.x;
    w_ls[(kq + 1) * GS + srow] = wv.y;
    w_ls[(kq + 2) * GS + srow] = wv.z;
    w_ls[(kq + 3) * GS + srow] = wv.w;
    __syncthreads();
#pragma unroll
    for (int kk = 0; kk < 32; ++kk) {
      const float4 av = *reinterpret_cast<const float4*>(&x_ls[kk * GS + r0]);
      const float4 bv = *reinterpret_cast<const float4*>(&w_ls[kk * GS + c0]);
      const float aa[4] = {av.x, av.y, av.z, av.w};
      const float bb[4] = {bv.x, bv.y, bv.z, bv.w};
#pragma unroll
      for (int i = 0; i < 4; ++i)
#pragma unroll
        for (int j = 0; j < 4; ++j) acc[i][j] = fmaf(aa[i], bb[j], acc[i][j]);
    }
    __syncthreads();
  }
#pragma unroll
  for (int i = 0; i < 4; ++i)
#pragma unroll
    for (int j = 0; j < 4; ++j) mo_ls[(r0 + i) * MOS + c0 + j] = acc[i][j];
  __syncthreads();

  // ------------- Phase 2: 2 LUs per wave (16 waves), r3-proven body ---------
  float waveacc = 0.f;

#pragma unroll 1
  for (int cc = 0; cc < 2; ++cc) {
    const int c = w * 2 + cc;
    const int cjv     = configs[c * D + lane];  // lane's row config index
    const int rowbase = cjv * MOS;

    float a[64];
#pragma unroll
    for (int j = 0; j < 64; ++j) {
      const int cj = __builtin_amdgcn_readlane(cjv, j);  // column config index
      a[j] = mo_ls[rowbase + cj];
    }

    int myslot = lane;   // virtual row-slot (tracks permutation for sign)
    float det  = 1.f;

#pragma unroll
    for (int k = 0; k < 64; ++k) {
      const float ak = a[k];
      // --- pivot selection: diagonal-first threshold pivoting ---
      unsigned long long dbal = __ballot(myslot == k);
      int   p  = (int)__builtin_ctzll(dbal);
      float pv = readlane_f(ak, p);

      if (!(fabsf(pv) > TAU)) {  // wave-uniform, rare (~8%)
        const bool act = (myslot >= k);
        unsigned long long cbal = __ballot(act && (fabsf(ak) > TAU));
        if (cbal == 0ull) {      // very rare: all candidates tiny -> true max
          float v = act ? fabsf(ak) : -1.f;
#pragma unroll
          for (int off = 32; off; off >>= 1) v = fmaxf(v, __shfl_xor(v, off));
          cbal = __ballot(act && (fabsf(ak) == v));
          if (cbal == 0ull) cbal = __ballot(act);  // paranoia
        }
        p  = (int)__builtin_ctzll(cbal);
        pv = readlane_f(ak, p);
        // swap + sign (LAPACK p!=k rule in slot space)
        const int sp = __builtin_amdgcn_readlane(myslot, p);
        if (sp != k) det = -det;
        myslot = (lane == p) ? k : ((myslot == k) ? sp : myslot);
      }

      float invp;
      if (pv != 0.f) {
        invp = __builtin_amdgcn_rcpf(pv);  // 1-ulp rcp; no NR (27x margin)
        det *= pv;
      } else {
        det  = 0.f;   // singular: freeze (invp=0 -> no-op updates)
        invp = 0.f;
      }

      const float m = (myslot > k) ? ak * invp : 0.f;  // retired rows: no-op
#pragma unroll
      for (int j = k + 1; j < 64; ++j)
        a[j] = fmaf(-m, readlane_f(a[j], p), a[j]);
    }
    waveacc += det * W_ci[c];
  }

  if (lane == 0) partial[w] = waveacc;
  __syncthreads();
  if (t == 0) {
    float s = 0.f;
#pragma unroll
    for (int i = 0; i < 16; ++i) s += partial[i];
    out[b] = s;
  }
}

extern "C" void kernel_launch(void* const* d_in, const int* in_sizes, int n_in,
                              void* d_out, int out_size, void* d_ws, size_t ws_size,
                              hipStream_t stream) {
  (void)in_sizes; (void)n_in; (void)d_ws; (void)ws_size; (void)out_size;
  const float* x       = (const float*)d_in[0];
  const float* W_mo    = (const float*)d_in[1];
  const float* W_ci    = (const float*)d_in[2];
  const int*   configs = (const int*)d_in[3];
  float*       out     = (float*)d_out;
  hipLaunchKernelGGL(wavenet_kernel, dim3(1024), dim3(1024), 0, stream,
                     x, W_mo, W_ci, configs, out);
}